// Round 15
// baseline (158.027 us; speedup 1.0000x reference)
//
#include <hip/hip_runtime.h>
#include <math.h>

#define D 128
#define MAXBIN 1600      // >= ceil(N/32); N=50000 -> 1563

typedef __attribute__((ext_vector_type(8))) short short8;
typedef __attribute__((ext_vector_type(4))) float f32x4;
typedef __attribute__((ext_vector_type(2))) float f32x2;

__device__ __forceinline__ ushort f2bf(float f) {
    uint u = __float_as_uint(f);
    u += 0x7FFFu + ((u >> 16) & 1u);       // round-to-nearest-even
    return (ushort)(u >> 16);
}
__device__ __forceinline__ float bf2f(ushort h) { return __uint_as_float(((uint)h) << 16); }
__device__ __forceinline__ float lo2f(uint u) { return __uint_as_float(u << 16); }
__device__ __forceinline__ float hi2f(uint u) { return __uint_as_float(u & 0xFFFF0000u); }

// ---------------------------------------------------------------------------
// Convert the 4 weight matrices (4*128*128) to bf16.
// ---------------------------------------------------------------------------
__global__ void convertW_kernel(
    const float* __restrict__ Wq, const float* __restrict__ Wk,
    const float* __restrict__ Wv, const float* __restrict__ Ws,
    ushort* __restrict__ wb)
{
    int i = blockIdx.x * 256 + threadIdx.x;
    if (i < 16384) {                        // 4 matrices * 4096 float4
        int m = i >> 12;
        const float* W = (m == 0) ? Wq : (m == 1) ? Wk : (m == 2) ? Wv : Ws;
        float4 f = ((const float4*)W)[i & 4095];
        ushort4 h;
        h.x = f2bf(f.x); h.y = f2bf(f.y); h.z = f2bf(f.z); h.w = f2bf(f.w);
        ((ushort4*)wb)[i] = h;
    }
}

// ---------------------------------------------------------------------------
// FUSED kernel: blocks [0,EBK) = bucket-HIST (8192 edges each, LDS atomics
// only -- hbin ALIASES the xs LDS so the kernel stays at 32KB LDS); blocks
// [EBK, EBK+MB) = mfma. Hist blocks drain fast; mfma backfills.
// GEMM (FROZEN numerics since R10): 8 waves, 64 rows/block; x-tile staged
// to LDS bf16, XOR-swizzled both sides. Outputs qb bf16 / kvrow (k fp8,
// v bf16) / out = x + skip.
// ---------------------------------------------------------------------------
__global__ __launch_bounds__(512) void fused_mfma_hist(
    const float* __restrict__ x, const ushort* __restrict__ wb,
    const float* __restrict__ bq, const float* __restrict__ bk,
    const float* __restrict__ bv, const float* __restrict__ bsk,
    ushort* __restrict__ qb, uchar* __restrict__ kvrow,
    float* __restrict__ out, int N,
    const int* __restrict__ dst, int* __restrict__ ghist,
    int E, int EBK, int NBIN)
{
    __shared__ __align__(16) uchar  xs[64 * 256];      // x-tile bf16 OR hist bins
    __shared__ __align__(16) ushort stg[8][16][64];    // epilogue staging

    const int bid = blockIdx.x;
    if (bid < EBK) {
        // ---------------- bucket-hist block (8192 edges) ----------------
        int* hbin = (int*)xs;                          // alias: 6.4KB of 16KB
        for (int j = threadIdx.x; j < NBIN; j += 512) hbin[j] = 0;
        __syncthreads();
        const int base = bid * 8192;
        #pragma unroll
        for (int k = 0; k < 16; ++k) {
            const int e = base + k * 512 + (int)threadIdx.x;
            if (e < E) atomicAdd(&hbin[dst[e] >> 5], 1);
        }
        __syncthreads();
        int* gh = ghist + (size_t)bid * NBIN;
        for (int j = threadIdx.x; j < NBIN; j += 512) gh[j] = hbin[j];
        return;
    }
    const int mb = bid - EBK;                          // mfma block index

    const int t = threadIdx.x;
    const int w = t >> 6, l = t & 63;
    const int mat = w >> 1;
    const int col0 = (w & 1) * 64;
    const int r0 = mb * 64;
    const int lr = l & 15, lg = l >> 4;

    // ---- stage x rows r0..r0+63 -> bf16, swizzled (4 rounds of 8B/thread) ----
    #pragma unroll
    for (int rr = 0; rr < 4; ++rr) {
        const int idx = rr * 512 + t;        // 0..2047 (64 rows x 32 float4-chunks)
        const int row = idx >> 5;
        const int c4  = idx & 31;
        float4 f = make_float4(0.f, 0.f, 0.f, 0.f);
        const int gr = r0 + row;
        if (gr < N) f = *(const float4*)(x + (size_t)gr * D + c4 * 4);
        uint2 h;
        h.x = (uint)f2bf(f.x) | ((uint)f2bf(f.y) << 16);
        h.y = (uint)f2bf(f.z) | ((uint)f2bf(f.w) << 16);
        const int baddr = (row * 256 + c4 * 8) ^ ((row & 7) << 4);
        *(uint2*)(xs + baddr) = h;
    }
    __syncthreads();

    const ushort* W = wb + (size_t)mat * (D * D);
    const float* bias = (mat == 0) ? bq : (mat == 1) ? bk : (mat == 2) ? bv : bsk;

    float bi[4];
    #pragma unroll
    for (int ct = 0; ct < 4; ++ct) bi[ct] = bias[col0 + ct * 16 + lr];

    f32x4 acc[4][4];
    #pragma unroll
    for (int rt = 0; rt < 4; ++rt)
        #pragma unroll
        for (int ct = 0; ct < 4; ++ct)
            acc[rt][ct] = (f32x4){0.f, 0.f, 0.f, 0.f};

    #pragma unroll
    for (int ks = 0; ks < 4; ++ks) {
        const int kbyte = ks * 64 + lg * 16;
        short8 b[4];
        #pragma unroll
        for (int ct = 0; ct < 4; ++ct)
            b[ct] = *(const short8*)(W + (size_t)(col0 + ct * 16 + lr) * D + ks * 32 + lg * 8);
        short8 a[4];
        #pragma unroll
        for (int rt = 0; rt < 4; ++rt) {
            const int rowL = rt * 16 + lr;
            a[rt] = *(const short8*)(xs + ((rowL * 256 + kbyte) ^ ((rowL & 7) << 4)));
        }
        #pragma unroll
        for (int rt = 0; rt < 4; ++rt)
            #pragma unroll
            for (int ct = 0; ct < 4; ++ct)
                acc[rt][ct] = __builtin_amdgcn_mfma_f32_16x16x32_bf16(
                    a[rt], b[ct], acc[rt][ct], 0, 0, 0);
    }

    // Epilogue: 4 chunks of 16 rows; same-wave LDS write->read.
    for (int rt = 0; rt < 4; ++rt) {
        #pragma unroll
        for (int ct = 0; ct < 4; ++ct) {
            const int colL = ct * 16 + lr;
            const int cch = colL >> 3, cin = colL & 7;
            #pragma unroll
            for (int r = 0; r < 4; ++r) {
                const int rowL = lg * 4 + r;
                stg[w][rowL][((cch ^ (rowL & 7)) << 3) + cin] =
                    f2bf(acc[rt][ct][r] + bi[ct]);
            }
        }
        #pragma unroll
        for (int rr = 0; rr < 2; ++rr) {
            const int rowL = rr * 8 + (l >> 3);
            const int c = l & 7;
            const int p = c ^ (rowL & 7);
            uint4 hv = *(const uint4*)&stg[w][rowL][p << 3];
            const int row_g = r0 + rt * 16 + rowL;
            if (row_g < N) {
                if (mat == 0) {
                    *(uint4*)(qb + (size_t)row_g * D + col0 + c * 8) = hv;
                } else if (mat == 1) {
                    const uint* hu = (const uint*)&hv;
                    uint w0 = 0, w1 = 0;
                    w0 = __builtin_amdgcn_cvt_pk_fp8_f32(lo2f(hu[0]), hi2f(hu[0]), w0, false);
                    w0 = __builtin_amdgcn_cvt_pk_fp8_f32(lo2f(hu[1]), hi2f(hu[1]), w0, true);
                    w1 = __builtin_amdgcn_cvt_pk_fp8_f32(lo2f(hu[2]), hi2f(hu[2]), w1, false);
                    w1 = __builtin_amdgcn_cvt_pk_fp8_f32(lo2f(hu[3]), hi2f(hu[3]), w1, true);
                    uint2 pk; pk.x = w0; pk.y = w1;
                    *(uint2*)(kvrow + (size_t)row_g * 384 + col0 + c * 8) = pk;
                } else if (mat == 2) {
                    *(uint4*)(kvrow + (size_t)row_g * 384 + 128 + 2 * col0 + 16 * c) = hv;
                } else {
                    const ushort* hs = (const ushort*)&hv;
                    const float4* xr = (const float4*)(x + (size_t)row_g * D + col0 + c * 8);
                    float4 x0 = xr[0], x1 = xr[1];
                    float4 o0, o1;
                    o0.x = x0.x + bf2f(hs[0]); o0.y = x0.y + bf2f(hs[1]);
                    o0.z = x0.z + bf2f(hs[2]); o0.w = x0.w + bf2f(hs[3]);
                    o1.x = x1.x + bf2f(hs[4]); o1.y = x1.y + bf2f(hs[5]);
                    o1.z = x1.z + bf2f(hs[6]); o1.w = x1.w + bf2f(hs[7]);
                    float4* orow = (float4*)(out + (size_t)row_g * D + col0 + c * 8);
                    orow[0] = o0; orow[1] = o1;
                }
            }
        }
    }
}

// ---------------------------------------------------------------------------
// Per-bin exclusive prefix over edge-blocks, THREAD per bin (coalesced:
// adjacent threads touch adjacent ints at every k). Writes totals to T.
// ---------------------------------------------------------------------------
__global__ __launch_bounds__(256) void binscan_kernel(
    int* __restrict__ ghist, int* __restrict__ T, int NBIN, int EBK)
{
    const int b = blockIdx.x * 256 + threadIdx.x;
    if (b >= NBIN) return;
    int run = 0;
    for (int k = 0; k < EBK; ++k) {
        int* p = ghist + (size_t)k * NBIN + b;
        const int v = *p;
        *p = run;
        run += v;
    }
    T[b] = run;
}

// ---------------------------------------------------------------------------
// Exclusive scan of bin totals -> bucket start offsets; Tofs[NBIN] = E.
// ---------------------------------------------------------------------------
__global__ void tscan_kernel(const int* __restrict__ T, int* __restrict__ Tofs, int NBIN)
{
    const int lane = threadIdx.x;   // 64 threads
    int base = 0;
    for (int s = 0; s < NBIN; s += 64) {
        const int idx = s + lane;
        int v = (idx < NBIN) ? T[idx] : 0;
        const int orig = v;
        #pragma unroll
        for (int off = 1; off < 64; off <<= 1) {
            int u = __shfl_up(v, off);
            if (lane >= off) v += u;
        }
        if (idx < NBIN) Tofs[idx] = base + v - orig;
        base += __shfl(v, 63);
    }
    if (lane == 0) Tofs[NBIN] = base;    // == E
}

// ---------------------------------------------------------------------------
// Bucket scatter: block ri seeds LDS cursors from Tofs + its scanned ghist
// row, then places its 8192 edges into bucket-sorted arrays (LDS atomics;
// blocks own disjoint global ranges per bucket by construction).
// ---------------------------------------------------------------------------
__global__ __launch_bounds__(512) void bucket_scatter_kernel(
    const int* __restrict__ src, const int* __restrict__ dst,
    const int* __restrict__ ghist, const int* __restrict__ Tofs,
    int* __restrict__ ssrc, ushort* __restrict__ sdst, int E, int NBIN)
{
    __shared__ int cur[MAXBIN];
    const int ri = blockIdx.x;
    const int* gh = ghist + (size_t)ri * NBIN;
    for (int j = threadIdx.x; j < NBIN; j += 512) cur[j] = Tofs[j] + gh[j];
    __syncthreads();
    const int base = ri * 8192;
    #pragma unroll
    for (int k = 0; k < 16; ++k) {
        const int e = base + k * 512 + (int)threadIdx.x;
        if (e < E) {
            const int d = dst[e];
            const int p = atomicAdd(&cur[d >> 5], 1);
            ssrc[p] = src[e] * 384;
            sdst[p] = (ushort)d;
        }
    }
}

// ---------------------------------------------------------------------------
// Finalize: one block per bucket (32 nodes). Exact per-node counts + prefix
// via 32 LDS counters; rewrite edge_src per-dst-contiguous; emit
// counts/offsets.
// ---------------------------------------------------------------------------
__global__ __launch_bounds__(512) void finalize_kernel(
    const int* __restrict__ ssrc, const ushort* __restrict__ sdst,
    const int* __restrict__ Tofs, int* __restrict__ edge_src,
    int* __restrict__ counts, int* __restrict__ offsets, int NBIN, int N)
{
    __shared__ int cnt[32], pref[32], cur[32];
    const int b = blockIdx.x;
    const int t = threadIdx.x;
    const int start = Tofs[b];
    const int end   = Tofs[b + 1];

    if (t < 32) cnt[t] = 0;
    __syncthreads();
    for (int e = start + t; e < end; e += 512)
        atomicAdd(&cnt[sdst[e] & 31], 1);
    __syncthreads();
    if (t < 64) {
        int v = (t < 32) ? cnt[t] : 0;
        #pragma unroll
        for (int off = 1; off < 32; off <<= 1) {
            int u = __shfl_up(v, off);
            if ((t & 63) >= off) v += u;
        }
        if (t < 32) { pref[t] = v - cnt[t]; cur[t] = v - cnt[t]; }
    }
    __syncthreads();
    for (int e = start + t; e < end; e += 512) {
        const int ld = sdst[e] & 31;
        const int p = atomicAdd(&cur[ld], 1);
        edge_src[start + p] = ssrc[e];
    }
    if (t < 32) {
        const int node = b * 32 + t;
        if (node < N) {
            counts[node]  = cnt[t];
            offsets[node] = start + pref[t];
        }
    }
}

// ---------------------------------------------------------------------------
// Attention (FROZEN numerics since R9: absmax margin is 3%).
// One wave per destination node, four edges in flight (slot = lane>>4),
// ld = lane&15 owns dims 8*ld..8*ld+7. k fp8 e4m3 (8B) + v bf16 (16B).
// No running max; cross-slot merge is a plain sum.
// ---------------------------------------------------------------------------
__global__ __launch_bounds__(256) void attn_kernel(
    const ushort* __restrict__ qb, const uchar* __restrict__ kvrow,
    const int* __restrict__ counts, const int* __restrict__ offsets,
    const int* __restrict__ edge_src, float* __restrict__ out, int N)
{
    const int lane = threadIdx.x & 63;
    const int slot = lane >> 4;
    const int ld   = lane & 15;
    const int wv   = threadIdx.x >> 6;
    const int i    = blockIdx.x * 4 + wv;
    if (i >= N) return;

    const float scale = 0.17677669529663687f;   // 1/sqrt(32)
    const uint4 qa = *(const uint4*)(qb + (size_t)i * D + 8 * ld);
    float qf[8];
    qf[0] = lo2f(qa.x) * scale; qf[1] = hi2f(qa.x) * scale;
    qf[2] = lo2f(qa.y) * scale; qf[3] = hi2f(qa.y) * scale;
    qf[4] = lo2f(qa.z) * scale; qf[5] = hi2f(qa.z) * scale;
    qf[6] = lo2f(qa.w) * scale; qf[7] = hi2f(qa.w) * scale;

    const int beg = offsets[i];
    const int cnt = counts[i];

    float l = 0.f;
    float av[8] = {0.f, 0.f, 0.f, 0.f, 0.f, 0.f, 0.f, 0.f};

    if (cnt > 0) {
        const int last = beg + cnt - 1;
        const uchar* kb = kvrow + 8 * ld;
        const uchar* vb = kvrow + 128 + 16 * ld;

        uint2 kk; uint4 vv;
        {
            const int off = edge_src[min(beg + slot, last)];
            kk = *(const uint2*)(kb + off);
            vv = *(const uint4*)(vb + off);
        }

        for (int e = 0; e < cnt; e += 4) {
            uint2 nk; uint4 nv;
            {
                const int off = edge_src[min(beg + e + 4 + slot, last)];
                nk = *(const uint2*)(kb + off);
                nv = *(const uint4*)(vb + off);
            }

            const f32x2 k01 = __builtin_amdgcn_cvt_pk_f32_fp8(kk.x, false);
            const f32x2 k23 = __builtin_amdgcn_cvt_pk_f32_fp8(kk.x, true);
            const f32x2 k45 = __builtin_amdgcn_cvt_pk_f32_fp8(kk.y, false);
            const f32x2 k67 = __builtin_amdgcn_cvt_pk_f32_fp8(kk.y, true);
            float dp;
            dp  = qf[0] * k01.x + qf[1] * k01.y;
            dp += qf[2] * k23.x + qf[3] * k23.y;
            dp += qf[4] * k45.x + qf[5] * k45.y;
            dp += qf[6] * k67.x + qf[7] * k67.y;
            dp += __shfl_xor(dp, 1);
            dp += __shfl_xor(dp, 2);

            const float p = (e + slot < cnt) ? __expf(dp) : 0.f;

            l += p;
            av[0] = fmaf(p, lo2f(vv.x), av[0]);
            av[1] = fmaf(p, hi2f(vv.x), av[1]);
            av[2] = fmaf(p, lo2f(vv.y), av[2]);
            av[3] = fmaf(p, hi2f(vv.y), av[3]);
            av[4] = fmaf(p, lo2f(vv.z), av[4]);
            av[5] = fmaf(p, hi2f(vv.z), av[5]);
            av[6] = fmaf(p, lo2f(vv.w), av[6]);
            av[7] = fmaf(p, hi2f(vv.w), av[7]);
            kk = nk; vv = nv;
        }
    }

    #pragma unroll
    for (int dist = 16; dist <= 32; dist <<= 1) {
        l += __shfl_xor(l, dist);
        #pragma unroll
        for (int d = 0; d < 8; ++d) av[d] += __shfl_xor(av[d], dist);
    }

    if (slot == 0) {
        const float inv = 1.0f / (l + 1e-16f);
        float4* orow = (float4*)(out + (size_t)i * D + 8 * ld);
        float4 o0 = orow[0], o1 = orow[1];
        o0.x += av[0] * inv; o0.y += av[1] * inv;
        o0.z += av[2] * inv; o0.w += av[3] * inv;
        o1.x += av[4] * inv; o1.y += av[5] * inv;
        o1.z += av[6] * inv; o1.w += av[7] * inv;
        orow[0] = o0; orow[1] = o1;
    }
}

// ---------------------------------------------------------------------------
extern "C" void kernel_launch(void* const* d_in, const int* in_sizes, int n_in,
                              void* d_out, int out_size, void* d_ws, size_t ws_size,
                              hipStream_t stream)
{
    const float* x   = (const float*)d_in[0];
    const int*   ei  = (const int*)d_in[1];    // [2][E], row0=src, row1=dst
    const float* Wq  = (const float*)d_in[2];
    const float* bq  = (const float*)d_in[3];
    const float* Wk  = (const float*)d_in[4];
    const float* bk  = (const float*)d_in[5];
    const float* Wv  = (const float*)d_in[6];
    const float* bv  = (const float*)d_in[7];
    const float* Wsk = (const float*)d_in[8];
    const float* bsk = (const float*)d_in[9];
    float* out = (float*)d_out;

    const int N = in_sizes[0] / D;
    const int E = in_sizes[1] / 2;
    const int NBIN = (N + 31) / 32;               // buckets of 32 nodes
    const int EBK  = (E + 8191) / 8192;           // edge blocks (8192 edges)

    // workspace layout (~41 MB)
    char* ws = (char*)d_ws;
    size_t o = 0;
    ushort* wb      = (ushort*)(ws + o); o += (size_t)4 * D * D * sizeof(ushort);
    ushort* qb      = (ushort*)(ws + o); o += (size_t)N * D * sizeof(ushort);
    uchar*  kvrow   = (uchar*)(ws + o);  o += (size_t)N * 384;
    o = (o + 255) & ~(size_t)255;
    int*    ghist   = (int*)(ws + o);    o += (size_t)EBK * NBIN * sizeof(int);
    int*    T       = (int*)(ws + o);    o += (size_t)NBIN * sizeof(int);
    int*    Tofs    = (int*)(ws + o);    o += (size_t)(NBIN + 1) * sizeof(int);
    int*    ssrc    = (int*)(ws + o);    o += (size_t)E * sizeof(int);
    ushort* sdst    = (ushort*)(ws + o); o += (size_t)E * sizeof(ushort);
    o = (o + 255) & ~(size_t)255;
    int*    counts  = (int*)(ws + o);    o += (size_t)N * sizeof(int);
    int*    offsets = (int*)(ws + o);    o += (size_t)N * sizeof(int);
    int*    edge_src= (int*)(ws + o);    o += (size_t)E * sizeof(int);

    convertW_kernel<<<64, 256, 0, stream>>>(Wq, Wk, Wv, Wsk, wb);

    const int MB = (N + 63) / 64;                 // mfma blocks (64 rows each)
    fused_mfma_hist<<<EBK + MB, 512, 0, stream>>>(
        x, wb, bq, bk, bv, bsk, qb, kvrow, out, N,
        ei + E, ghist, E, EBK, NBIN);

    binscan_kernel<<<(NBIN + 255) / 256, 256, 0, stream>>>(ghist, T, NBIN, EBK);
    tscan_kernel<<<1, 64, 0, stream>>>(T, Tofs, NBIN);

    bucket_scatter_kernel<<<EBK, 512, 0, stream>>>(
        ei, ei + E, ghist, Tofs, ssrc, sdst, E, NBIN);

    finalize_kernel<<<NBIN, 512, 0, stream>>>(
        ssrc, sdst, Tofs, edge_src, counts, offsets, NBIN, N);

    attn_kernel<<<(N + 3) / 4, 256, 0, stream>>>(qb, kvrow, counts, offsets, edge_src, out, N);
}

// Round 16
// 137.416 us; speedup vs baseline: 1.1500x; 1.1500x over previous
//
#include <hip/hip_runtime.h>
#include <math.h>

#define D 128

typedef __attribute__((ext_vector_type(8))) short short8;
typedef __attribute__((ext_vector_type(4))) float f32x4;
typedef __attribute__((ext_vector_type(2))) float f32x2;

__device__ __forceinline__ ushort f2bf(float f) {
    uint u = __float_as_uint(f);
    u += 0x7FFFu + ((u >> 16) & 1u);       // round-to-nearest-even
    return (ushort)(u >> 16);
}
__device__ __forceinline__ float bf2f(ushort h) { return __uint_as_float(((uint)h) << 16); }
__device__ __forceinline__ float lo2f(uint u) { return __uint_as_float(u << 16); }
__device__ __forceinline__ float hi2f(uint u) { return __uint_as_float(u & 0xFFFF0000u); }

// ---------------------------------------------------------------------------
// Convert the 4 weight matrices (4*128*128) to bf16 and zero counts.
// ---------------------------------------------------------------------------
__global__ void convertW_kernel(
    const float* __restrict__ Wq, const float* __restrict__ Wk,
    const float* __restrict__ Wv, const float* __restrict__ Ws,
    ushort* __restrict__ wb, int* __restrict__ counts, int N)
{
    int i = blockIdx.x * 256 + threadIdx.x;
    if (i < 16384) {                        // 4 matrices * 4096 float4
        int m = i >> 12;
        const float* W = (m == 0) ? Wq : (m == 1) ? Wk : (m == 2) ? Wv : Ws;
        float4 f = ((const float4*)W)[i & 4095];
        ushort4 h;
        h.x = f2bf(f.x); h.y = f2bf(f.y); h.z = f2bf(f.z); h.w = f2bf(f.w);
        ((ushort4*)wb)[i] = h;
    } else if (i < 16384 + N) {
        counts[i - 16384] = 0;
    }
}

// ---------------------------------------------------------------------------
// FUSED kernel, RANK-FIRST mapping: bid < RB -> rank block; else mfma.
// All rank blocks are resident from dispatch start (the ~50us device-atomic
// wall begins immediately); mfma blocks co-reside and hide inside it
// (disjoint resources: MFMA/LDS pipes vs atomic fabric).
// Rank block: 2048 edges, 4/thread, 4 independent atomicAdds in flight:
//   rank[e] = atomicAdd(&counts[dst[e]], 1)   (counts ends as degree)
// GEMM (FROZEN numerics since R10): 8 waves, 64 rows/block; x-tile staged
// to LDS bf16, XOR-swizzled both sides. Outputs qb bf16 / kvrow (k fp8,
// v bf16) / out = x + skip.
// ---------------------------------------------------------------------------
__global__ __launch_bounds__(512) void fused_mfma_rank(
    const float* __restrict__ x, const ushort* __restrict__ wb,
    const float* __restrict__ bq, const float* __restrict__ bk,
    const float* __restrict__ bv, const float* __restrict__ bsk,
    ushort* __restrict__ qb, uchar* __restrict__ kvrow,
    float* __restrict__ out, int N,
    const int* __restrict__ dst, int* __restrict__ counts,
    int* __restrict__ rank, int E, int RB)
{
    __shared__ __align__(16) uchar  xs[64 * 256];      // swizzled x-tile bf16, 16KB
    __shared__ __align__(16) ushort stg[8][16][64];    // epilogue staging, 16KB

    const int bid = blockIdx.x;
    if (bid < RB) {
        // ---------------- rank pass: 2048 edges/block, 4/thread ----------------
        const int base = bid * 2048 + (int)threadIdx.x * 4;
        if (base + 3 < E) {
            const int4 d4 = *(const int4*)(dst + base);
            int4 r4;
            r4.x = atomicAdd(&counts[d4.x], 1);
            r4.y = atomicAdd(&counts[d4.y], 1);
            r4.z = atomicAdd(&counts[d4.z], 1);
            r4.w = atomicAdd(&counts[d4.w], 1);
            *(int4*)(rank + base) = r4;
        } else if (base < E) {
            for (int e = base; e < E; ++e)
                rank[e] = atomicAdd(&counts[dst[e]], 1);
        }
        return;
    }
    const int mb = bid - RB;                           // mfma block index

    const int t = threadIdx.x;
    const int w = t >> 6, l = t & 63;
    const int mat = w >> 1;
    const int col0 = (w & 1) * 64;
    const int r0 = mb * 64;
    const int lr = l & 15, lg = l >> 4;

    // ---- stage x rows r0..r0+63 -> bf16, swizzled (4 rounds of 8B/thread) ----
    #pragma unroll
    for (int rr = 0; rr < 4; ++rr) {
        const int idx = rr * 512 + t;        // 0..2047 (64 rows x 32 float4-chunks)
        const int row = idx >> 5;
        const int c4  = idx & 31;
        float4 f = make_float4(0.f, 0.f, 0.f, 0.f);
        const int gr = r0 + row;
        if (gr < N) f = *(const float4*)(x + (size_t)gr * D + c4 * 4);
        uint2 h;
        h.x = (uint)f2bf(f.x) | ((uint)f2bf(f.y) << 16);
        h.y = (uint)f2bf(f.z) | ((uint)f2bf(f.w) << 16);
        const int baddr = (row * 256 + c4 * 8) ^ ((row & 7) << 4);
        *(uint2*)(xs + baddr) = h;
    }
    __syncthreads();

    const ushort* W = wb + (size_t)mat * (D * D);
    const float* bias = (mat == 0) ? bq : (mat == 1) ? bk : (mat == 2) ? bv : bsk;

    float bi[4];
    #pragma unroll
    for (int ct = 0; ct < 4; ++ct) bi[ct] = bias[col0 + ct * 16 + lr];

    f32x4 acc[4][4];
    #pragma unroll
    for (int rt = 0; rt < 4; ++rt)
        #pragma unroll
        for (int ct = 0; ct < 4; ++ct)
            acc[rt][ct] = (f32x4){0.f, 0.f, 0.f, 0.f};

    #pragma unroll
    for (int ks = 0; ks < 4; ++ks) {
        const int kbyte = ks * 64 + lg * 16;
        short8 b[4];
        #pragma unroll
        for (int ct = 0; ct < 4; ++ct)
            b[ct] = *(const short8*)(W + (size_t)(col0 + ct * 16 + lr) * D + ks * 32 + lg * 8);
        short8 a[4];
        #pragma unroll
        for (int rt = 0; rt < 4; ++rt) {
            const int rowL = rt * 16 + lr;
            a[rt] = *(const short8*)(xs + ((rowL * 256 + kbyte) ^ ((rowL & 7) << 4)));
        }
        #pragma unroll
        for (int rt = 0; rt < 4; ++rt)
            #pragma unroll
            for (int ct = 0; ct < 4; ++ct)
                acc[rt][ct] = __builtin_amdgcn_mfma_f32_16x16x32_bf16(
                    a[rt], b[ct], acc[rt][ct], 0, 0, 0);
    }

    // Epilogue: 4 chunks of 16 rows; same-wave LDS write->read.
    for (int rt = 0; rt < 4; ++rt) {
        #pragma unroll
        for (int ct = 0; ct < 4; ++ct) {
            const int colL = ct * 16 + lr;
            const int cch = colL >> 3, cin = colL & 7;
            #pragma unroll
            for (int r = 0; r < 4; ++r) {
                const int rowL = lg * 4 + r;
                stg[w][rowL][((cch ^ (rowL & 7)) << 3) + cin] =
                    f2bf(acc[rt][ct][r] + bi[ct]);
            }
        }
        #pragma unroll
        for (int rr = 0; rr < 2; ++rr) {
            const int rowL = rr * 8 + (l >> 3);
            const int c = l & 7;
            const int p = c ^ (rowL & 7);
            uint4 hv = *(const uint4*)&stg[w][rowL][p << 3];
            const int row_g = r0 + rt * 16 + rowL;
            if (row_g < N) {
                if (mat == 0) {
                    *(uint4*)(qb + (size_t)row_g * D + col0 + c * 8) = hv;
                } else if (mat == 1) {
                    const uint* hu = (const uint*)&hv;
                    uint w0 = 0, w1 = 0;
                    w0 = __builtin_amdgcn_cvt_pk_fp8_f32(lo2f(hu[0]), hi2f(hu[0]), w0, false);
                    w0 = __builtin_amdgcn_cvt_pk_fp8_f32(lo2f(hu[1]), hi2f(hu[1]), w0, true);
                    w1 = __builtin_amdgcn_cvt_pk_fp8_f32(lo2f(hu[2]), hi2f(hu[2]), w1, false);
                    w1 = __builtin_amdgcn_cvt_pk_fp8_f32(lo2f(hu[3]), hi2f(hu[3]), w1, true);
                    uint2 pk; pk.x = w0; pk.y = w1;
                    *(uint2*)(kvrow + (size_t)row_g * 384 + col0 + c * 8) = pk;
                } else if (mat == 2) {
                    *(uint4*)(kvrow + (size_t)row_g * 384 + 128 + 2 * col0 + 16 * c) = hv;
                } else {
                    const ushort* hs = (const ushort*)&hv;
                    const float4* xr = (const float4*)(x + (size_t)row_g * D + col0 + c * 8);
                    float4 x0 = xr[0], x1 = xr[1];
                    float4 o0, o1;
                    o0.x = x0.x + bf2f(hs[0]); o0.y = x0.y + bf2f(hs[1]);
                    o0.z = x0.z + bf2f(hs[2]); o0.w = x0.w + bf2f(hs[3]);
                    o1.x = x1.x + bf2f(hs[4]); o1.y = x1.y + bf2f(hs[5]);
                    o1.z = x1.z + bf2f(hs[6]); o1.w = x1.w + bf2f(hs[7]);
                    float4* orow = (float4*)(out + (size_t)row_g * D + col0 + c * 8);
                    orow[0] = o0; orow[1] = o1;
                }
            }
        }
    }
}

// ---------------------------------------------------------------------------
// Scans (counts -> exclusive offsets)
// ---------------------------------------------------------------------------
__global__ __launch_bounds__(1024) void scan_blocks(
    const int* __restrict__ counts, int* __restrict__ offsets,
    int* __restrict__ partials, int n)
{
    __shared__ int sm[1024];
    int tid = threadIdx.x;
    int i = blockIdx.x * 1024 + tid;
    int v = (i < n) ? counts[i] : 0;
    sm[tid] = v;
    __syncthreads();
    for (int off = 1; off < 1024; off <<= 1) {
        int tv = (tid >= off) ? sm[tid - off] : 0;
        __syncthreads();
        sm[tid] += tv;
        __syncthreads();
    }
    if (i < n) offsets[i] = sm[tid] - v;
    if (tid == 1023) partials[blockIdx.x] = sm[1023];
}

__global__ __launch_bounds__(1024) void scan_add(
    int* __restrict__ offsets, const int* __restrict__ partials, int n)
{
    __shared__ int base_sm;
    if (threadIdx.x < 64) {
        int v = 0;
        for (int j = threadIdx.x; j < (int)blockIdx.x; j += 64) v += partials[j];
        #pragma unroll
        for (int off = 32; off; off >>= 1) v += __shfl_down(v, off);
        if (threadIdx.x == 0) base_sm = v;
    }
    __syncthreads();
    int i = blockIdx.x * 1024 + threadIdx.x;
    if (i < n) offsets[i] += base_sm;
}

// ---------------------------------------------------------------------------
// Scatter WITHOUT atomics: pos = offsets[dst] + rank.
// ---------------------------------------------------------------------------
__global__ void scatter_kernel(
    const int* __restrict__ src, const int* __restrict__ dst,
    const int* __restrict__ rank, const int* __restrict__ offsets,
    int* __restrict__ edge_src, int E)
{
    const int t = blockIdx.x * 256 + threadIdx.x;
    const int base = t * 4;
    if (base + 3 < E) {
        const int4 s4 = ((const int4*)src)[t];
        const int4 d4 = ((const int4*)dst)[t];
        const int4 r4 = ((const int4*)rank)[t];
        edge_src[offsets[d4.x] + r4.x] = s4.x * 384;
        edge_src[offsets[d4.y] + r4.y] = s4.y * 384;
        edge_src[offsets[d4.z] + r4.z] = s4.z * 384;
        edge_src[offsets[d4.w] + r4.w] = s4.w * 384;
    } else if (base < E) {
        for (int e = base; e < E; ++e)
            edge_src[offsets[dst[e]] + rank[e]] = src[e] * 384;
    }
}

// ---------------------------------------------------------------------------
// Attention (FROZEN numerics since R9: absmax margin is 3%).
// One wave per destination node, four edges in flight (slot = lane>>4),
// ld = lane&15 owns dims 8*ld..8*ld+7. k fp8 e4m3 (8B) + v bf16 (16B).
// No running max; cross-slot merge is a plain sum.
// ---------------------------------------------------------------------------
__global__ __launch_bounds__(256) void attn_kernel(
    const ushort* __restrict__ qb, const uchar* __restrict__ kvrow,
    const int* __restrict__ counts, const int* __restrict__ offsets,
    const int* __restrict__ edge_src, float* __restrict__ out, int N)
{
    const int lane = threadIdx.x & 63;
    const int slot = lane >> 4;
    const int ld   = lane & 15;
    const int wv   = threadIdx.x >> 6;
    const int i    = blockIdx.x * 4 + wv;
    if (i >= N) return;

    const float scale = 0.17677669529663687f;   // 1/sqrt(32)
    const uint4 qa = *(const uint4*)(qb + (size_t)i * D + 8 * ld);
    float qf[8];
    qf[0] = lo2f(qa.x) * scale; qf[1] = hi2f(qa.x) * scale;
    qf[2] = lo2f(qa.y) * scale; qf[3] = hi2f(qa.y) * scale;
    qf[4] = lo2f(qa.z) * scale; qf[5] = hi2f(qa.z) * scale;
    qf[6] = lo2f(qa.w) * scale; qf[7] = hi2f(qa.w) * scale;

    const int beg = offsets[i];
    const int cnt = counts[i];

    float l = 0.f;
    float av[8] = {0.f, 0.f, 0.f, 0.f, 0.f, 0.f, 0.f, 0.f};

    if (cnt > 0) {
        const int last = beg + cnt - 1;
        const uchar* kb = kvrow + 8 * ld;
        const uchar* vb = kvrow + 128 + 16 * ld;

        uint2 kk; uint4 vv;
        {
            const int off = edge_src[min(beg + slot, last)];
            kk = *(const uint2*)(kb + off);
            vv = *(const uint4*)(vb + off);
        }

        for (int e = 0; e < cnt; e += 4) {
            uint2 nk; uint4 nv;
            {
                const int off = edge_src[min(beg + e + 4 + slot, last)];
                nk = *(const uint2*)(kb + off);
                nv = *(const uint4*)(vb + off);
            }

            const f32x2 k01 = __builtin_amdgcn_cvt_pk_f32_fp8(kk.x, false);
            const f32x2 k23 = __builtin_amdgcn_cvt_pk_f32_fp8(kk.x, true);
            const f32x2 k45 = __builtin_amdgcn_cvt_pk_f32_fp8(kk.y, false);
            const f32x2 k67 = __builtin_amdgcn_cvt_pk_f32_fp8(kk.y, true);
            float dp;
            dp  = qf[0] * k01.x + qf[1] * k01.y;
            dp += qf[2] * k23.x + qf[3] * k23.y;
            dp += qf[4] * k45.x + qf[5] * k45.y;
            dp += qf[6] * k67.x + qf[7] * k67.y;
            dp += __shfl_xor(dp, 1);
            dp += __shfl_xor(dp, 2);

            const float p = (e + slot < cnt) ? __expf(dp) : 0.f;

            l += p;
            av[0] = fmaf(p, lo2f(vv.x), av[0]);
            av[1] = fmaf(p, hi2f(vv.x), av[1]);
            av[2] = fmaf(p, lo2f(vv.y), av[2]);
            av[3] = fmaf(p, hi2f(vv.y), av[3]);
            av[4] = fmaf(p, lo2f(vv.z), av[4]);
            av[5] = fmaf(p, hi2f(vv.z), av[5]);
            av[6] = fmaf(p, lo2f(vv.w), av[6]);
            av[7] = fmaf(p, hi2f(vv.w), av[7]);
            kk = nk; vv = nv;
        }
    }

    #pragma unroll
    for (int dist = 16; dist <= 32; dist <<= 1) {
        l += __shfl_xor(l, dist);
        #pragma unroll
        for (int d = 0; d < 8; ++d) av[d] += __shfl_xor(av[d], dist);
    }

    if (slot == 0) {
        const float inv = 1.0f / (l + 1e-16f);
        float4* orow = (float4*)(out + (size_t)i * D + 8 * ld);
        float4 o0 = orow[0], o1 = orow[1];
        o0.x += av[0] * inv; o0.y += av[1] * inv;
        o0.z += av[2] * inv; o0.w += av[3] * inv;
        o1.x += av[4] * inv; o1.y += av[5] * inv;
        o1.z += av[6] * inv; o1.w += av[7] * inv;
        orow[0] = o0; orow[1] = o1;
    }
}

// ---------------------------------------------------------------------------
extern "C" void kernel_launch(void* const* d_in, const int* in_sizes, int n_in,
                              void* d_out, int out_size, void* d_ws, size_t ws_size,
                              hipStream_t stream)
{
    const float* x   = (const float*)d_in[0];
    const int*   ei  = (const int*)d_in[1];    // [2][E], row0=src, row1=dst
    const float* Wq  = (const float*)d_in[2];
    const float* bq  = (const float*)d_in[3];
    const float* Wk  = (const float*)d_in[4];
    const float* bk  = (const float*)d_in[5];
    const float* Wv  = (const float*)d_in[6];
    const float* bv  = (const float*)d_in[7];
    const float* Wsk = (const float*)d_in[8];
    const float* bsk = (const float*)d_in[9];
    float* out = (float*)d_out;

    const int N = in_sizes[0] / D;
    const int E = in_sizes[1] / 2;

    // workspace layout (~43 MB)
    char* ws = (char*)d_ws;
    size_t o = 0;
    ushort* wb      = (ushort*)(ws + o); o += (size_t)4 * D * D * sizeof(ushort);
    ushort* qb      = (ushort*)(ws + o); o += (size_t)N * D * sizeof(ushort);
    uchar*  kvrow   = (uchar*)(ws + o);  o += (size_t)N * 384;
    o = (o + 255) & ~(size_t)255;
    int*   counts   = (int*)(ws + o);    o += (size_t)N * sizeof(int);
    int*   offsets  = (int*)(ws + o);    o += (size_t)N * sizeof(int);
    int*   rank     = (int*)(ws + o);    o += (size_t)E * sizeof(int);
    int*   partials = (int*)(ws + o);    o += 4096;
    int*   edge_src = (int*)(ws + o);    o += (size_t)E * sizeof(int);

    convertW_kernel<<<(16384 + N + 255) / 256, 256, 0, stream>>>(
        Wq, Wk, Wv, Wsk, wb, counts, N);

    const int MB = (N + 63) / 64;                 // mfma blocks (64 rows each)
    const int RB = (E + 2047) / 2048;             // rank blocks (2048 edges each)
    fused_mfma_rank<<<RB + MB, 512, 0, stream>>>(
        x, wb, bq, bk, bv, bsk, qb, kvrow, out, N,
        ei + E, counts, rank, E, RB);

    int nb = (N + 1023) / 1024;
    scan_blocks<<<nb, 1024, 0, stream>>>(counts, offsets, partials, N);
    scan_add<<<nb, 1024, 0, stream>>>(offsets, partials, N);

    scatter_kernel<<<(E / 4 + 255) / 256, 256, 0, stream>>>(
        ei, ei + E, rank, offsets, edge_src, E);

    attn_kernel<<<(N + 3) / 4, 256, 0, stream>>>(qb, kvrow, counts, offsets, edge_src, out, N);
}

// Round 17
// 125.179 us; speedup vs baseline: 1.2624x; 1.0978x over previous
//
#include <hip/hip_runtime.h>
#include <math.h>

#define D 128

typedef __attribute__((ext_vector_type(8))) short short8;
typedef __attribute__((ext_vector_type(4))) float f32x4;
typedef __attribute__((ext_vector_type(2))) float f32x2;

__device__ __forceinline__ ushort f2bf(float f) {
    uint u = __float_as_uint(f);
    u += 0x7FFFu + ((u >> 16) & 1u);       // round-to-nearest-even
    return (ushort)(u >> 16);
}
__device__ __forceinline__ float bf2f(ushort h) { return __uint_as_float(((uint)h) << 16); }
__device__ __forceinline__ float lo2f(uint u) { return __uint_as_float(u << 16); }
__device__ __forceinline__ float hi2f(uint u) { return __uint_as_float(u & 0xFFFF0000u); }

// ---------------------------------------------------------------------------
// Convert the 4 weight matrices (4*128*128) to bf16 and zero counts.
// ---------------------------------------------------------------------------
__global__ void convertW_kernel(
    const float* __restrict__ Wq, const float* __restrict__ Wk,
    const float* __restrict__ Wv, const float* __restrict__ Ws,
    ushort* __restrict__ wb, int* __restrict__ counts, int N)
{
    int i = blockIdx.x * 256 + threadIdx.x;
    if (i < 16384) {                        // 4 matrices * 4096 float4
        int m = i >> 12;
        const float* W = (m == 0) ? Wq : (m == 1) ? Wk : (m == 2) ? Wv : Ws;
        float4 f = ((const float4*)W)[i & 4095];
        ushort4 h;
        h.x = f2bf(f.x); h.y = f2bf(f.y); h.z = f2bf(f.z); h.w = f2bf(f.w);
        ((ushort4*)wb)[i] = h;
    } else if (i < 16384 + N) {
        counts[i - 16384] = 0;
    }
}

// ---------------------------------------------------------------------------
// FUSED kernel, INTERLEAVED block mapping (measured-best of {mfma-first,
// rank-first, %3}: R11=66-72, R16=66, R12=58.9us): bid%3==1 -> rank block
// (ri=bid/3), else mfma block. Rank and mfma blocks co-reside on every CU
// for the whole dispatch; the compute-bound GEMM hides under the
// atomic-throughput-bound rank pass (disjoint pipes).
// Rank block: 512 threads x 4 edges, 4 independent atomicAdds in flight:
//   rank[e] = atomicAdd(&counts[dst[e]], 1)   (counts ends as degree)
// GEMM (FROZEN numerics since R10): 8 waves, 64 rows/block; x-tile staged
// to LDS bf16, XOR-swizzled both sides. Outputs qb bf16 / kvrow (k fp8,
// v bf16) / out = x + skip.
// ---------------------------------------------------------------------------
__global__ __launch_bounds__(512) void fused_mfma_rank(
    const float* __restrict__ x, const ushort* __restrict__ wb,
    const float* __restrict__ bq, const float* __restrict__ bk,
    const float* __restrict__ bv, const float* __restrict__ bsk,
    ushort* __restrict__ qb, uchar* __restrict__ kvrow,
    float* __restrict__ out, int N,
    const int* __restrict__ dst, int* __restrict__ counts,
    int* __restrict__ rank, int E, int RB)
{
    __shared__ __align__(16) uchar  xs[64 * 256];      // swizzled x-tile bf16, 16KB
    __shared__ __align__(16) ushort stg[8][16][64];    // epilogue staging, 16KB

    const int bid = blockIdx.x;
    const int ri  = bid / 3;
    if ((bid % 3 == 1) && (ri < RB)) {
        // ---------------- rank pass: 2048 edges/block, 4/thread ----------------
        const int base = ri * 2048 + (int)threadIdx.x * 4;
        if (base + 3 < E) {
            const int4 d4 = *(const int4*)(dst + base);
            int4 r4;
            r4.x = atomicAdd(&counts[d4.x], 1);
            r4.y = atomicAdd(&counts[d4.y], 1);
            r4.z = atomicAdd(&counts[d4.z], 1);
            r4.w = atomicAdd(&counts[d4.w], 1);
            *(int4*)(rank + base) = r4;
        } else if (base < E) {
            for (int e = base; e < E; ++e)
                rank[e] = atomicAdd(&counts[dst[e]], 1);
        }
        return;
    }
    const int mb = bid - min((bid + 1) / 3, RB);       // mfma block index

    const int t = threadIdx.x;
    const int w = t >> 6, l = t & 63;
    const int mat = w >> 1;
    const int col0 = (w & 1) * 64;
    const int r0 = mb * 64;
    const int lr = l & 15, lg = l >> 4;

    // ---- stage x rows r0..r0+63 -> bf16, swizzled (4 rounds of 8B/thread) ----
    #pragma unroll
    for (int rr = 0; rr < 4; ++rr) {
        const int idx = rr * 512 + t;        // 0..2047 (64 rows x 32 float4-chunks)
        const int row = idx >> 5;
        const int c4  = idx & 31;
        float4 f = make_float4(0.f, 0.f, 0.f, 0.f);
        const int gr = r0 + row;
        if (gr < N) f = *(const float4*)(x + (size_t)gr * D + c4 * 4);
        uint2 h;
        h.x = (uint)f2bf(f.x) | ((uint)f2bf(f.y) << 16);
        h.y = (uint)f2bf(f.z) | ((uint)f2bf(f.w) << 16);
        const int baddr = (row * 256 + c4 * 8) ^ ((row & 7) << 4);
        *(uint2*)(xs + baddr) = h;
    }
    __syncthreads();

    const ushort* W = wb + (size_t)mat * (D * D);
    const float* bias = (mat == 0) ? bq : (mat == 1) ? bk : (mat == 2) ? bv : bsk;

    float bi[4];
    #pragma unroll
    for (int ct = 0; ct < 4; ++ct) bi[ct] = bias[col0 + ct * 16 + lr];

    f32x4 acc[4][4];
    #pragma unroll
    for (int rt = 0; rt < 4; ++rt)
        #pragma unroll
        for (int ct = 0; ct < 4; ++ct)
            acc[rt][ct] = (f32x4){0.f, 0.f, 0.f, 0.f};

    #pragma unroll
    for (int ks = 0; ks < 4; ++ks) {
        const int kbyte = ks * 64 + lg * 16;
        short8 b[4];
        #pragma unroll
        for (int ct = 0; ct < 4; ++ct)
            b[ct] = *(const short8*)(W + (size_t)(col0 + ct * 16 + lr) * D + ks * 32 + lg * 8);
        short8 a[4];
        #pragma unroll
        for (int rt = 0; rt < 4; ++rt) {
            const int rowL = rt * 16 + lr;
            a[rt] = *(const short8*)(xs + ((rowL * 256 + kbyte) ^ ((rowL & 7) << 4)));
        }
        #pragma unroll
        for (int rt = 0; rt < 4; ++rt)
            #pragma unroll
            for (int ct = 0; ct < 4; ++ct)
                acc[rt][ct] = __builtin_amdgcn_mfma_f32_16x16x32_bf16(
                    a[rt], b[ct], acc[rt][ct], 0, 0, 0);
    }

    // Epilogue: 4 chunks of 16 rows; same-wave LDS write->read.
    for (int rt = 0; rt < 4; ++rt) {
        #pragma unroll
        for (int ct = 0; ct < 4; ++ct) {
            const int colL = ct * 16 + lr;
            const int cch = colL >> 3, cin = colL & 7;
            #pragma unroll
            for (int r = 0; r < 4; ++r) {
                const int rowL = lg * 4 + r;
                stg[w][rowL][((cch ^ (rowL & 7)) << 3) + cin] =
                    f2bf(acc[rt][ct][r] + bi[ct]);
            }
        }
        #pragma unroll
        for (int rr = 0; rr < 2; ++rr) {
            const int rowL = rr * 8 + (l >> 3);
            const int c = l & 7;
            const int p = c ^ (rowL & 7);
            uint4 hv = *(const uint4*)&stg[w][rowL][p << 3];
            const int row_g = r0 + rt * 16 + rowL;
            if (row_g < N) {
                if (mat == 0) {
                    *(uint4*)(qb + (size_t)row_g * D + col0 + c * 8) = hv;
                } else if (mat == 1) {
                    const uint* hu = (const uint*)&hv;
                    uint w0 = 0, w1 = 0;
                    w0 = __builtin_amdgcn_cvt_pk_fp8_f32(lo2f(hu[0]), hi2f(hu[0]), w0, false);
                    w0 = __builtin_amdgcn_cvt_pk_fp8_f32(lo2f(hu[1]), hi2f(hu[1]), w0, true);
                    w1 = __builtin_amdgcn_cvt_pk_fp8_f32(lo2f(hu[2]), hi2f(hu[2]), w1, false);
                    w1 = __builtin_amdgcn_cvt_pk_fp8_f32(lo2f(hu[3]), hi2f(hu[3]), w1, true);
                    uint2 pk; pk.x = w0; pk.y = w1;
                    *(uint2*)(kvrow + (size_t)row_g * 384 + col0 + c * 8) = pk;
                } else if (mat == 2) {
                    *(uint4*)(kvrow + (size_t)row_g * 384 + 128 + 2 * col0 + 16 * c) = hv;
                } else {
                    const ushort* hs = (const ushort*)&hv;
                    const float4* xr = (const float4*)(x + (size_t)row_g * D + col0 + c * 8);
                    float4 x0 = xr[0], x1 = xr[1];
                    float4 o0, o1;
                    o0.x = x0.x + bf2f(hs[0]); o0.y = x0.y + bf2f(hs[1]);
                    o0.z = x0.z + bf2f(hs[2]); o0.w = x0.w + bf2f(hs[3]);
                    o1.x = x1.x + bf2f(hs[4]); o1.y = x1.y + bf2f(hs[5]);
                    o1.z = x1.z + bf2f(hs[6]); o1.w = x1.w + bf2f(hs[7]);
                    float4* orow = (float4*)(out + (size_t)row_g * D + col0 + c * 8);
                    orow[0] = o0; orow[1] = o1;
                }
            }
        }
    }
}

// ---------------------------------------------------------------------------
// Scans (counts -> exclusive offsets)
// ---------------------------------------------------------------------------
__global__ __launch_bounds__(1024) void scan_blocks(
    const int* __restrict__ counts, int* __restrict__ offsets,
    int* __restrict__ partials, int n)
{
    __shared__ int sm[1024];
    int tid = threadIdx.x;
    int i = blockIdx.x * 1024 + tid;
    int v = (i < n) ? counts[i] : 0;
    sm[tid] = v;
    __syncthreads();
    for (int off = 1; off < 1024; off <<= 1) {
        int tv = (tid >= off) ? sm[tid - off] : 0;
        __syncthreads();
        sm[tid] += tv;
        __syncthreads();
    }
    if (i < n) offsets[i] = sm[tid] - v;
    if (tid == 1023) partials[blockIdx.x] = sm[1023];
}

__global__ __launch_bounds__(1024) void scan_add(
    int* __restrict__ offsets, const int* __restrict__ partials, int n)
{
    __shared__ int base_sm;
    if (threadIdx.x < 64) {
        int v = 0;
        for (int j = threadIdx.x; j < (int)blockIdx.x; j += 64) v += partials[j];
        #pragma unroll
        for (int off = 32; off; off >>= 1) v += __shfl_down(v, off);
        if (threadIdx.x == 0) base_sm = v;
    }
    __syncthreads();
    int i = blockIdx.x * 1024 + threadIdx.x;
    if (i < n) offsets[i] += base_sm;
}

// ---------------------------------------------------------------------------
// Scatter WITHOUT atomics: pos = offsets[dst] + rank.
// ---------------------------------------------------------------------------
__global__ void scatter_kernel(
    const int* __restrict__ src, const int* __restrict__ dst,
    const int* __restrict__ rank, const int* __restrict__ offsets,
    int* __restrict__ edge_src, int E)
{
    const int t = blockIdx.x * 256 + threadIdx.x;
    const int base = t * 4;
    if (base + 3 < E) {
        const int4 s4 = ((const int4*)src)[t];
        const int4 d4 = ((const int4*)dst)[t];
        const int4 r4 = ((const int4*)rank)[t];
        edge_src[offsets[d4.x] + r4.x] = s4.x * 384;
        edge_src[offsets[d4.y] + r4.y] = s4.y * 384;
        edge_src[offsets[d4.z] + r4.z] = s4.z * 384;
        edge_src[offsets[d4.w] + r4.w] = s4.w * 384;
    } else if (base < E) {
        for (int e = base; e < E; ++e)
            edge_src[offsets[dst[e]] + rank[e]] = src[e] * 384;
    }
}

// ---------------------------------------------------------------------------
// Attention (FROZEN numerics since R9: absmax margin is 3%).
// One wave per destination node, four edges in flight (slot = lane>>4),
// ld = lane&15 owns dims 8*ld..8*ld+7. k fp8 e4m3 (8B) + v bf16 (16B).
// No running max; cross-slot merge is a plain sum.
// ---------------------------------------------------------------------------
__global__ __launch_bounds__(256) void attn_kernel(
    const ushort* __restrict__ qb, const uchar* __restrict__ kvrow,
    const int* __restrict__ counts, const int* __restrict__ offsets,
    const int* __restrict__ edge_src, float* __restrict__ out, int N)
{
    const int lane = threadIdx.x & 63;
    const int slot = lane >> 4;
    const int ld   = lane & 15;
    const int wv   = threadIdx.x >> 6;
    const int i    = blockIdx.x * 4 + wv;
    if (i >= N) return;

    const float scale = 0.17677669529663687f;   // 1/sqrt(32)
    const uint4 qa = *(const uint4*)(qb + (size_t)i * D + 8 * ld);
    float qf[8];
    qf[0] = lo2f(qa.x) * scale; qf[1] = hi2f(qa.x) * scale;
    qf[2] = lo2f(qa.y) * scale; qf[3] = hi2f(qa.y) * scale;
    qf[4] = lo2f(qa.z) * scale; qf[5] = hi2f(qa.z) * scale;
    qf[6] = lo2f(qa.w) * scale; qf[7] = hi2f(qa.w) * scale;

    const int beg = offsets[i];
    const int cnt = counts[i];

    float l = 0.f;
    float av[8] = {0.f, 0.f, 0.f, 0.f, 0.f, 0.f, 0.f, 0.f};

    if (cnt > 0) {
        const int last = beg + cnt - 1;
        const uchar* kb = kvrow + 8 * ld;
        const uchar* vb = kvrow + 128 + 16 * ld;

        uint2 kk; uint4 vv;
        {
            const int off = edge_src[min(beg + slot, last)];
            kk = *(const uint2*)(kb + off);
            vv = *(const uint4*)(vb + off);
        }

        for (int e = 0; e < cnt; e += 4) {
            uint2 nk; uint4 nv;
            {
                const int off = edge_src[min(beg + e + 4 + slot, last)];
                nk = *(const uint2*)(kb + off);
                nv = *(const uint4*)(vb + off);
            }

            const f32x2 k01 = __builtin_amdgcn_cvt_pk_f32_fp8(kk.x, false);
            const f32x2 k23 = __builtin_amdgcn_cvt_pk_f32_fp8(kk.x, true);
            const f32x2 k45 = __builtin_amdgcn_cvt_pk_f32_fp8(kk.y, false);
            const f32x2 k67 = __builtin_amdgcn_cvt_pk_f32_fp8(kk.y, true);
            float dp;
            dp  = qf[0] * k01.x + qf[1] * k01.y;
            dp += qf[2] * k23.x + qf[3] * k23.y;
            dp += qf[4] * k45.x + qf[5] * k45.y;
            dp += qf[6] * k67.x + qf[7] * k67.y;
            dp += __shfl_xor(dp, 1);
            dp += __shfl_xor(dp, 2);

            const float p = (e + slot < cnt) ? __expf(dp) : 0.f;

            l += p;
            av[0] = fmaf(p, lo2f(vv.x), av[0]);
            av[1] = fmaf(p, hi2f(vv.x), av[1]);
            av[2] = fmaf(p, lo2f(vv.y), av[2]);
            av[3] = fmaf(p, hi2f(vv.y), av[3]);
            av[4] = fmaf(p, lo2f(vv.z), av[4]);
            av[5] = fmaf(p, hi2f(vv.z), av[5]);
            av[6] = fmaf(p, lo2f(vv.w), av[6]);
            av[7] = fmaf(p, hi2f(vv.w), av[7]);
            kk = nk; vv = nv;
        }
    }

    #pragma unroll
    for (int dist = 16; dist <= 32; dist <<= 1) {
        l += __shfl_xor(l, dist);
        #pragma unroll
        for (int d = 0; d < 8; ++d) av[d] += __shfl_xor(av[d], dist);
    }

    if (slot == 0) {
        const float inv = 1.0f / (l + 1e-16f);
        float4* orow = (float4*)(out + (size_t)i * D + 8 * ld);
        float4 o0 = orow[0], o1 = orow[1];
        o0.x += av[0] * inv; o0.y += av[1] * inv;
        o0.z += av[2] * inv; o0.w += av[3] * inv;
        o1.x += av[4] * inv; o1.y += av[5] * inv;
        o1.z += av[6] * inv; o1.w += av[7] * inv;
        orow[0] = o0; orow[1] = o1;
    }
}

// ---------------------------------------------------------------------------
extern "C" void kernel_launch(void* const* d_in, const int* in_sizes, int n_in,
                              void* d_out, int out_size, void* d_ws, size_t ws_size,
                              hipStream_t stream)
{
    const float* x   = (const float*)d_in[0];
    const int*   ei  = (const int*)d_in[1];    // [2][E], row0=src, row1=dst
    const float* Wq  = (const float*)d_in[2];
    const float* bq  = (const float*)d_in[3];
    const float* Wk  = (const float*)d_in[4];
    const float* bk  = (const float*)d_in[5];
    const float* Wv  = (const float*)d_in[6];
    const float* bv  = (const float*)d_in[7];
    const float* Wsk = (const float*)d_in[8];
    const float* bsk = (const float*)d_in[9];
    float* out = (float*)d_out;

    const int N = in_sizes[0] / D;
    const int E = in_sizes[1] / 2;

    // workspace layout (~43 MB)
    char* ws = (char*)d_ws;
    size_t o = 0;
    ushort* wb      = (ushort*)(ws + o); o += (size_t)4 * D * D * sizeof(ushort);
    ushort* qb      = (ushort*)(ws + o); o += (size_t)N * D * sizeof(ushort);
    uchar*  kvrow   = (uchar*)(ws + o);  o += (size_t)N * 384;
    o = (o + 255) & ~(size_t)255;
    int*   counts   = (int*)(ws + o);    o += (size_t)N * sizeof(int);
    int*   offsets  = (int*)(ws + o);    o += (size_t)N * sizeof(int);
    int*   rank     = (int*)(ws + o);    o += (size_t)E * sizeof(int);
    int*   partials = (int*)(ws + o);    o += 4096;
    int*   edge_src = (int*)(ws + o);    o += (size_t)E * sizeof(int);

    convertW_kernel<<<(16384 + N + 255) / 256, 256, 0, stream>>>(
        Wq, Wk, Wv, Wsk, wb, counts, N);

    const int MB = (N + 63) / 64;                 // mfma blocks (64 rows each)
    const int RB = (E + 2047) / 2048;             // rank blocks (2048 edges each)
    fused_mfma_rank<<<MB + RB, 512, 0, stream>>>(
        x, wb, bq, bk, bv, bsk, qb, kvrow, out, N,
        ei + E, counts, rank, E, RB);

    int nb = (N + 1023) / 1024;
    scan_blocks<<<nb, 1024, 0, stream>>>(counts, offsets, partials, N);
    scan_add<<<nb, 1024, 0, stream>>>(offsets, partials, N);

    scatter_kernel<<<(E / 4 + 255) / 256, 256, 0, stream>>>(
        ei, ei + E, rank, offsets, edge_src, E);

    attn_kernel<<<(N + 3) / 4, 256, 0, stream>>>(qb, kvrow, counts, offsets, edge_src, out, N);
}